// Round 9
// baseline (72.985 us; speedup 1.0000x reference)
//
#include <hip/hip_runtime.h>
#include <hip/hip_bf16.h>

#define IN_F 8192
#define OUT_F 8192
#define NROWS 128
#define CB 256
#define NSL 8                  // split-K slices
#define KSLICE (IN_F / NSL)    // 1024
#define NTB 64                 // n-tile per block
#define NIT (KSLICE / 32)      // 32 K-iterations per block

using bf8   = __attribute__((ext_vector_type(8))) short;  // 8 bf16 (4 VGPRs)
using f32x4 = __attribute__((ext_vector_type(4))) float;  // 4 fp32 accum

__device__ inline float bf2f(unsigned int u) {
    union { unsigned int i; float f; } v; v.i = u << 16; return v.f;
}
__device__ inline unsigned short f2bf(float f) {
    __hip_bfloat16 h = __float2bfloat16(f);
    return *reinterpret_cast<unsigned short*>(&h);
}
__device__ inline void unpack8(uint4 v, float* f) {
    f[0] = bf2f(v.x & 0xffffu); f[1] = bf2f(v.x >> 16);
    f[2] = bf2f(v.y & 0xffffu); f[3] = bf2f(v.y >> 16);
    f[4] = bf2f(v.z & 0xffffu); f[5] = bf2f(v.z >> 16);
    f[6] = bf2f(v.w & 0xffffu); f[7] = bf2f(v.w >> 16);
}

#define FWHT_SCALE 0.011048543456039806f  // 1/sqrt(8192)

// 3-level in-register FWHT-8192: 256 threads x 32 elems. (round-5 proven)
#define FWHT_STAGES(LOJ, HIJ)                                             \
    _Pragma("unroll")                                                     \
    for (int hb = (LOJ); hb < (HIJ); ++hb) {                              \
        const int h = 1 << hb;                                            \
        _Pragma("unroll")                                                 \
        for (int j = 0; j < 32; ++j)                                      \
            if (!(j & h)) {                                               \
                float a = v[j], b = v[j | h];                             \
                v[j] = a + b; v[j | h] = a - b;                           \
            }                                                             \
    }

__device__ inline void fwht8192(float* v, float* lds, int t) {
    FWHT_STAGES(0, 5)
#pragma unroll
    for (int j = 0; j < 32; ++j) lds[j * 257 + t] = v[j];
    __syncthreads();
    {
        const int o = t & 31, uh = t >> 5;
        const int base = o * 257 + uh * 32;
#pragma unroll
        for (int k = 0; k < 32; ++k) v[k] = lds[base + k];
    }
    FWHT_STAGES(0, 4)
    __syncthreads();
    {
        const int o = t & 31, uh = t >> 5;
#pragma unroll
        for (int k = 0; k < 32; ++k)
            lds[o * 257 + (k & 15) * 16 + uh * 2 + (k >> 4)] = v[k];
    }
    __syncthreads();
    {
        const int o = t & 31, mh = t >> 5;
#pragma unroll
        for (int h2 = 0; h2 < 2; ++h2)
#pragma unroll
            for (int w = 0; w < 16; ++w)
                v[h2 * 16 + w] = lds[o * 257 + (mh * 2 + h2) * 16 + w];
    }
    FWHT_STAGES(0, 4)
    __syncthreads();
    {
        const int o = t & 31, mh = t >> 5;
#pragma unroll
        for (int h2 = 0; h2 < 2; ++h2) {
            const int M = 2 * mh + h2;
#pragma unroll
            for (int w = 0; w < 16; ++w) {
                const int i = w * 512 + M * 32 + o;
                const int q2 = (i >> 2) ^ (M & 7);
                lds[q2 * 4 + (o & 3)] = v[h2 * 16 + w];
            }
        }
    }
    __syncthreads();
#pragma unroll
    for (int j4 = 0; j4 < 8; ++j4) {
        const int q2 = (t * 8 + j4) ^ (t & 7);
        const float4 f = *reinterpret_cast<const float4*>(&lds[q2 * 4]);
        v[j4 * 4 + 0] = f.x; v[j4 * 4 + 1] = f.y;
        v[j4 * 4 + 2] = f.z; v[j4 * 4 + 3] = f.w;
    }
}

// ---- Kernel A: xt = fwht(input/scaleWH*SU) in MFMA-tiled bf16 layout ----
// Tiled layout: elem (r,k) at ((r>>4)*256 + (k>>5))*512 + ((k&31)>>3)*128
//               + (r&15)*8 + (k&7)   [ushort units]
__global__ __launch_bounds__(256) void k_pre3(const float* __restrict__ in,
                                              const float* __restrict__ scaleWH,
                                              const float* __restrict__ SU,
                                              unsigned short* __restrict__ xt) {
    __shared__ float lds[8224];
    const int r = blockIdx.x, t = threadIdx.x;
    float v[32];
    const float4* xp = reinterpret_cast<const float4*>(in + (size_t)r * IN_F);
    const float4* sp = reinterpret_cast<const float4*>(scaleWH);
    const float4* up = reinterpret_cast<const float4*>(SU);
#pragma unroll
    for (int q = 0; q < 8; ++q) {
        float4 x = xp[t * 8 + q], s = sp[t * 8 + q], u = up[t * 8 + q];
        v[q * 4 + 0] = x.x / s.x * u.x;
        v[q * 4 + 1] = x.y / s.y * u.y;
        v[q * 4 + 2] = x.z / s.z * u.z;
        v[q * 4 + 3] = x.w / s.w * u.w;
    }
    fwht8192(v, lds, t);
    const size_t base = ((size_t)(r >> 4) * 256 + t) * 512 + (r & 15) * 8;
#pragma unroll
    for (int q = 0; q < 4; ++q) {
        unsigned int w[4];
#pragma unroll
        for (int p = 0; p < 4; ++p) {
            unsigned int lo = f2bf(v[q * 8 + 2 * p]     * FWHT_SCALE);
            unsigned int hi = f2bf(v[q * 8 + 2 * p + 1] * FWHT_SCALE);
            w[p] = lo | (hi << 16);
        }
        *reinterpret_cast<uint4*>(xt + base + q * 128) = make_uint4(w[0], w[1], w[2], w[3]);
    }
}

// ---- Kernel B: barrier-free GEMM, fully-unrolled K-loop (compiler-pipelined)
// grid (128, NSL); 256 thr = 4 waves (2x2); block tile 128x64; K-step 32.
__global__ __launch_bounds__(256, 4) void k_gemm5(
        const unsigned short* __restrict__ xt,
        const int* __restrict__ Qidxs,
        const float* __restrict__ cb,
        const float* __restrict__ wscale,
        unsigned short* __restrict__ pout) {
    __shared__ __align__(16) unsigned short cbl[CB][8];
    const int tid = threadIdx.x;
    const int wave = tid >> 6, lane = tid & 63;
    const int wr = wave >> 1, wc = wave & 1;
    const int lr = lane & 15, lk8 = lane >> 4;
    const int n0 = blockIdx.x * NTB;
    const int ks0 = blockIdx.y * KSLICE;
    const int ksb = ks0 >> 5;
    const int QC = IN_F / 8;

    const float wsc = wscale[0];
    for (int e = tid; e < CB * 8; e += 256) cbl[e >> 3][e & 7] = f2bf(cb[e] * wsc);

    f32x4 acc[4][2];
#pragma unroll
    for (int mt = 0; mt < 4; ++mt)
#pragma unroll
        for (int nt = 0; nt < 2; ++nt) acc[mt][nt] = (f32x4){0.f, 0.f, 0.f, 0.f};

    const unsigned short* xw = xt + ((size_t)(wr * 4) * 256 + ksb) * 512 + lane * 8;
    const int* q0 = Qidxs + (size_t)(n0 + wc * 32 + lr) * QC + ks0 / 8 + lk8;
    const int* q1 = q0 + 16 * QC;
    __syncthreads();   // cbl ready

    // Fully unrolled: per-iteration SSA locals, no buffer copies; the
    // compiler hoists A/q loads ahead (VGPR-budget-bounded) and interleaves
    // cbl gathers with prior MFMAs. No barriers -> nothing drains vmcnt.
#pragma unroll
    for (int it = 0; it < NIT; ++it) {
        const int qa = q0[it * 4];
        const int qb = q1[it * 4];
        bf8 a0 = *reinterpret_cast<const bf8*>(xw + (0 * 256 + it) * 512);
        bf8 a1 = *reinterpret_cast<const bf8*>(xw + (1 * 256 + it) * 512);
        bf8 a2 = *reinterpret_cast<const bf8*>(xw + (2 * 256 + it) * 512);
        bf8 a3 = *reinterpret_cast<const bf8*>(xw + (3 * 256 + it) * 512);
        bf8 b0 = *(const bf8*)&cbl[qa][0];
        bf8 b1 = *(const bf8*)&cbl[qb][0];
        acc[0][0] = __builtin_amdgcn_mfma_f32_16x16x32_bf16(a0, b0, acc[0][0], 0, 0, 0);
        acc[0][1] = __builtin_amdgcn_mfma_f32_16x16x32_bf16(a0, b1, acc[0][1], 0, 0, 0);
        acc[1][0] = __builtin_amdgcn_mfma_f32_16x16x32_bf16(a1, b0, acc[1][0], 0, 0, 0);
        acc[1][1] = __builtin_amdgcn_mfma_f32_16x16x32_bf16(a1, b1, acc[1][1], 0, 0, 0);
        acc[2][0] = __builtin_amdgcn_mfma_f32_16x16x32_bf16(a2, b0, acc[2][0], 0, 0, 0);
        acc[2][1] = __builtin_amdgcn_mfma_f32_16x16x32_bf16(a2, b1, acc[2][1], 0, 0, 0);
        acc[3][0] = __builtin_amdgcn_mfma_f32_16x16x32_bf16(a3, b0, acc[3][0], 0, 0, 0);
        acc[3][1] = __builtin_amdgcn_mfma_f32_16x16x32_bf16(a3, b1, acc[3][1], 0, 0, 0);
    }

    // epilogue: C/D col=lane&15, row=(lane>>4)*4+reg; bf16 partial store
    unsigned short* ps = pout + (size_t)blockIdx.y * (NROWS * OUT_F);
#pragma unroll
    for (int mt = 0; mt < 4; ++mt) {
        const int row = wr * 64 + mt * 16 + lk8 * 4;
#pragma unroll
        for (int nt = 0; nt < 2; ++nt) {
            const int col = n0 + wc * 32 + nt * 16 + lr;
#pragma unroll
            for (int r2 = 0; r2 < 4; ++r2)
                ps[(size_t)(row + r2) * OUT_F + col] = f2bf(acc[mt][nt][r2]);
        }
    }
}

// ---- Kernel C: out = fwht(sum_slices)*SV + bias  [f32 out] ----
__global__ __launch_bounds__(256) void k_post2(const unsigned short* __restrict__ pin,
                                               const float* __restrict__ SV,
                                               const float* __restrict__ bias,
                                               float* __restrict__ out) {
    __shared__ float lds[8224];
    const int r = blockIdx.x, t = threadIdx.x;
    float v[32];
#pragma unroll
    for (int j = 0; j < 32; ++j) v[j] = 0.f;
#pragma unroll 1
    for (int sl = 0; sl < NSL; ++sl) {
        const uint4* p = reinterpret_cast<const uint4*>(
            pin + (size_t)sl * NROWS * OUT_F + (size_t)r * OUT_F + t * 32);
#pragma unroll
        for (int q = 0; q < 4; ++q) {
            float a[8];
            unpack8(p[q], a);
#pragma unroll
            for (int j = 0; j < 8; ++j) v[q * 8 + j] += a[j];
        }
    }
    fwht8192(v, lds, t);
    const float4* svp = reinterpret_cast<const float4*>(SV);
    const float4* bip = reinterpret_cast<const float4*>(bias);
    float4* op = reinterpret_cast<float4*>(out + (size_t)r * OUT_F);
#pragma unroll
    for (int q = 0; q < 8; ++q) {
        float4 sv = svp[t * 8 + q], bi = bip[t * 8 + q], o;
        o.x = v[q * 4 + 0] * FWHT_SCALE * sv.x + bi.x;
        o.y = v[q * 4 + 1] * FWHT_SCALE * sv.y + bi.y;
        o.z = v[q * 4 + 2] * FWHT_SCALE * sv.z + bi.z;
        o.w = v[q * 4 + 3] * FWHT_SCALE * sv.w + bi.w;
        op[t * 8 + q] = o;
    }
}

extern "C" void kernel_launch(void* const* d_in, const int* in_sizes, int n_in,
                              void* d_out, int out_size, void* d_ws, size_t ws_size,
                              hipStream_t stream) {
    const float* in      = (const float*)d_in[0];
    const int*   Qidxs   = (const int*)d_in[1];
    const float* cb      = (const float*)d_in[2];
    const float* scaleWH = (const float*)d_in[3];
    const float* SU      = (const float*)d_in[4];
    const float* SV      = (const float*)d_in[5];
    const float* wscale  = (const float*)d_in[6];
    const float* bias    = (const float*)d_in[7];
    float* out = (float*)d_out;

    unsigned short* xt    = (unsigned short*)d_ws;                    // 2 MB (tiled)
    unsigned short* parts = (unsigned short*)((char*)d_ws
                            + (size_t)NROWS * IN_F * 2);              // 16 MB

    k_pre3<<<NROWS, 256, 0, stream>>>(in, scaleWH, SU, xt);
    k_gemm5<<<dim3(OUT_F / NTB, NSL), 256, 0, stream>>>(xt, Qidxs, cb, wscale, parts);
    k_post2<<<NROWS, 256, 0, stream>>>(parts, SV, bias, out);
}

// Round 10
// 50.310 us; speedup vs baseline: 1.4507x; 1.4507x over previous
//
#include <hip/hip_runtime.h>
#include <hip/hip_bf16.h>

#define IN_F 8192
#define OUT_F 8192
#define NROWS 128
#define CB 256
#define NSL 8                  // split-K slices
#define KSLICE (IN_F / NSL)    // 1024
#define NTB 64                 // n-tile per block
#define NIT (KSLICE / 32)      // 32 K-iterations per block
#define QC (IN_F / 8)          // 1024 dwords per Qidxs row

using bf8   = __attribute__((ext_vector_type(8))) short;  // 8 bf16 (4 VGPRs)
using f32x4 = __attribute__((ext_vector_type(4))) float;  // 4 fp32 accum

typedef const __attribute__((address_space(1))) void* as1cv;
typedef __attribute__((address_space(3))) void* as3v;

__device__ inline float bf2f(unsigned int u) {
    union { unsigned int i; float f; } v; v.i = u << 16; return v.f;
}
__device__ inline unsigned short f2bf(float f) {
    __hip_bfloat16 h = __float2bfloat16(f);
    return *reinterpret_cast<unsigned short*>(&h);
}
__device__ inline void unpack8(uint4 v, float* f) {
    f[0] = bf2f(v.x & 0xffffu); f[1] = bf2f(v.x >> 16);
    f[2] = bf2f(v.y & 0xffffu); f[3] = bf2f(v.y >> 16);
    f[4] = bf2f(v.z & 0xffffu); f[5] = bf2f(v.z >> 16);
    f[6] = bf2f(v.w & 0xffffu); f[7] = bf2f(v.w >> 16);
}

#define FWHT_SCALE 0.011048543456039806f  // 1/sqrt(8192)

// 3-level in-register FWHT-8192: 256 threads x 32 elems. (round-5 proven)
#define FWHT_STAGES(LOJ, HIJ)                                             \
    _Pragma("unroll")                                                     \
    for (int hb = (LOJ); hb < (HIJ); ++hb) {                              \
        const int h = 1 << hb;                                            \
        _Pragma("unroll")                                                 \
        for (int j = 0; j < 32; ++j)                                      \
            if (!(j & h)) {                                               \
                float a = v[j], b = v[j | h];                             \
                v[j] = a + b; v[j | h] = a - b;                           \
            }                                                             \
    }

__device__ inline void fwht8192(float* v, float* lds, int t) {
    FWHT_STAGES(0, 5)
#pragma unroll
    for (int j = 0; j < 32; ++j) lds[j * 257 + t] = v[j];
    __syncthreads();
    {
        const int o = t & 31, uh = t >> 5;
        const int base = o * 257 + uh * 32;
#pragma unroll
        for (int k = 0; k < 32; ++k) v[k] = lds[base + k];
    }
    FWHT_STAGES(0, 4)
    __syncthreads();
    {
        const int o = t & 31, uh = t >> 5;
#pragma unroll
        for (int k = 0; k < 32; ++k)
            lds[o * 257 + (k & 15) * 16 + uh * 2 + (k >> 4)] = v[k];
    }
    __syncthreads();
    {
        const int o = t & 31, mh = t >> 5;
#pragma unroll
        for (int h2 = 0; h2 < 2; ++h2)
#pragma unroll
            for (int w = 0; w < 16; ++w)
                v[h2 * 16 + w] = lds[o * 257 + (mh * 2 + h2) * 16 + w];
    }
    FWHT_STAGES(0, 4)
    __syncthreads();
    {
        const int o = t & 31, mh = t >> 5;
#pragma unroll
        for (int h2 = 0; h2 < 2; ++h2) {
            const int M = 2 * mh + h2;
#pragma unroll
            for (int w = 0; w < 16; ++w) {
                const int i = w * 512 + M * 32 + o;
                const int q2 = (i >> 2) ^ (M & 7);
                lds[q2 * 4 + (o & 3)] = v[h2 * 16 + w];
            }
        }
    }
    __syncthreads();
#pragma unroll
    for (int j4 = 0; j4 < 8; ++j4) {
        const int q2 = (t * 8 + j4) ^ (t & 7);
        const float4 f = *reinterpret_cast<const float4*>(&lds[q2 * 4]);
        v[j4 * 4 + 0] = f.x; v[j4 * 4 + 1] = f.y;
        v[j4 * 4 + 2] = f.z; v[j4 * 4 + 3] = f.w;
    }
}

// ---- Kernel A: xt = fwht(input/scaleWH*SU) in MFMA-tiled bf16 layout ----
// Tiled layout: elem (r,k) at ((r>>4)*256 + (k>>5))*512 + ((k&31)>>3)*128
//               + (r&15)*8 + (k&7)   [ushort units]
__global__ __launch_bounds__(256) void k_pre3(const float* __restrict__ in,
                                              const float* __restrict__ scaleWH,
                                              const float* __restrict__ SU,
                                              unsigned short* __restrict__ xt) {
    __shared__ float lds[8224];
    const int r = blockIdx.x, t = threadIdx.x;
    float v[32];
    const float4* xp = reinterpret_cast<const float4*>(in + (size_t)r * IN_F);
    const float4* sp = reinterpret_cast<const float4*>(scaleWH);
    const float4* up = reinterpret_cast<const float4*>(SU);
#pragma unroll
    for (int q = 0; q < 8; ++q) {
        float4 x = xp[t * 8 + q], s = sp[t * 8 + q], u = up[t * 8 + q];
        v[q * 4 + 0] = x.x / s.x * u.x;
        v[q * 4 + 1] = x.y / s.y * u.y;
        v[q * 4 + 2] = x.z / s.z * u.z;
        v[q * 4 + 3] = x.w / s.w * u.w;
    }
    fwht8192(v, lds, t);
    const size_t base = ((size_t)(r >> 4) * 256 + t) * 512 + (r & 15) * 8;
#pragma unroll
    for (int q = 0; q < 4; ++q) {
        unsigned int w[4];
#pragma unroll
        for (int p = 0; p < 4; ++p) {
            unsigned int lo = f2bf(v[q * 8 + 2 * p]     * FWHT_SCALE);
            unsigned int hi = f2bf(v[q * 8 + 2 * p + 1] * FWHT_SCALE);
            w[p] = lo | (hi << 16);
        }
        *reinterpret_cast<uint4*>(xt + base + q * 128) = make_uint4(w[0], w[1], w[2], w[3]);
    }
}

// ---- Kernel B: GEMM with chunk-ahead LDS-staged Qidxs ----
// grid (128, NSL); 256 thr = 4 waves (2x2); block tile 128x64; K-step 32.
// Qidxs staged in 16-iteration chunks (16KB), double-buffered: the only
// barriers are at chunk boundaries, and they drain loads issued a full
// chunk (~4000 cyc) earlier. A direct-global (tiled layout, 1KB/wave).
__global__ __launch_bounds__(256, 4) void k_gemm6(
        const unsigned short* __restrict__ xt,
        const int* __restrict__ Qidxs,
        const float* __restrict__ cb,
        const float* __restrict__ wscale,
        unsigned short* __restrict__ pout) {
    __shared__ __align__(16) unsigned short cbl[CB][8];      // 4 KB
    __shared__ __align__(16) int Qlds[2][64 * 64];           // 2 x 16 KB
    const int tid = threadIdx.x;
    const int wave = tid >> 6, lane = tid & 63;
    const int wr = wave >> 1, wc = wave & 1;
    const int lr = lane & 15, lk8 = lane >> 4;
    const int n0 = blockIdx.x * NTB;
    const int ks0 = blockIdx.y * KSLICE;
    const int ksb = ks0 >> 5;
    const int c0 = ks0 >> 3;            // slice's first Qidxs dword col

    // stage one 64-row x 64-dword Qidxs chunk into Qlds[buf].
    // LDS dest linear (wave-uniform base + lane*16); source col-group
    // pre-swizzled by (row & 15) so the in-loop b32 reads are 2-way clean.
    auto stageQ = [&](int buf, int ch) {
#pragma unroll
        for (int j = 0; j < 4; ++j) {
            const int rl = wave * 16 + j * 4 + (lane >> 4);
            const int cgs = (lane & 15) ^ (rl & 15);
            const int* g = Qidxs + (size_t)(n0 + rl) * QC + c0 + ch * 64 + cgs * 4;
            as3v l = (as3v)(&Qlds[buf][(wave * 16 + j * 4) * 64]);
            __builtin_amdgcn_global_load_lds((as1cv)(const void*)g, l, 16, 0, 0);
        }
    };

    stageQ(0, 0);
    const float wsc = wscale[0];
    for (int e = tid; e < CB * 8; e += 256) cbl[e >> 3][e & 7] = f2bf(cb[e] * wsc);

    f32x4 acc[4][2];
#pragma unroll
    for (int mt = 0; mt < 4; ++mt)
#pragma unroll
        for (int nt = 0; nt < 2; ++nt) acc[mt][nt] = (f32x4){0.f, 0.f, 0.f, 0.f};

    const unsigned short* xw = xt + ((size_t)(wr * 4) * 256 + ksb) * 512 + lane * 8;
    __syncthreads();    // cbl + chunk 0 staged

    // per-iteration: 2 LDS q-reads (swizzle-corrected), 2 cbl gathers,
    // 4 contiguous A loads, 8 MFMA. Straight-line x16 per chunk.
#define COMPUTE_CHUNK(BUF, CH)                                                \
    _Pragma("unroll")                                                         \
    for (int itc = 0; itc < 16; ++itc) {                                      \
        const int it = (CH) * 16 + itc;                                       \
        const int qoff = ((itc ^ lr) << 2) + lk8;                             \
        const int qa = Qlds[BUF][(wc * 32 + lr) * 64 + qoff];                 \
        const int qb = Qlds[BUF][(wc * 32 + 16 + lr) * 64 + qoff];            \
        bf8 a0 = *reinterpret_cast<const bf8*>(xw + (0 * 256 + it) * 512);    \
        bf8 a1 = *reinterpret_cast<const bf8*>(xw + (1 * 256 + it) * 512);    \
        bf8 a2 = *reinterpret_cast<const bf8*>(xw + (2 * 256 + it) * 512);    \
        bf8 a3 = *reinterpret_cast<const bf8*>(xw + (3 * 256 + it) * 512);    \
        bf8 b0 = *(const bf8*)&cbl[qa][0];                                    \
        bf8 b1 = *(const bf8*)&cbl[qb][0];                                    \
        acc[0][0] = __builtin_amdgcn_mfma_f32_16x16x32_bf16(a0, b0, acc[0][0], 0, 0, 0); \
        acc[0][1] = __builtin_amdgcn_mfma_f32_16x16x32_bf16(a0, b1, acc[0][1], 0, 0, 0); \
        acc[1][0] = __builtin_amdgcn_mfma_f32_16x16x32_bf16(a1, b0, acc[1][0], 0, 0, 0); \
        acc[1][1] = __builtin_amdgcn_mfma_f32_16x16x32_bf16(a1, b1, acc[1][1], 0, 0, 0); \
        acc[2][0] = __builtin_amdgcn_mfma_f32_16x16x32_bf16(a2, b0, acc[2][0], 0, 0, 0); \
        acc[2][1] = __builtin_amdgcn_mfma_f32_16x16x32_bf16(a2, b1, acc[2][1], 0, 0, 0); \
        acc[3][0] = __builtin_amdgcn_mfma_f32_16x16x32_bf16(a3, b0, acc[3][0], 0, 0, 0); \
        acc[3][1] = __builtin_amdgcn_mfma_f32_16x16x32_bf16(a3, b1, acc[3][1], 0, 0, 0); \
    }

    stageQ(1, 1);            // chunk 1 in flight across chunk 0's compute
    COMPUTE_CHUNK(0, 0)
    __syncthreads();         // drains stage(1) — issued ~4000 cyc ago
    COMPUTE_CHUNK(1, 1)
#undef COMPUTE_CHUNK

    // epilogue: C/D col=lane&15, row=(lane>>4)*4+reg; bf16 partial store
    unsigned short* ps = pout + (size_t)blockIdx.y * (NROWS * OUT_F);
#pragma unroll
    for (int mt = 0; mt < 4; ++mt) {
        const int row = wr * 64 + mt * 16 + lk8 * 4;
#pragma unroll
        for (int nt = 0; nt < 2; ++nt) {
            const int col = n0 + wc * 32 + nt * 16 + lr;
#pragma unroll
            for (int r2 = 0; r2 < 4; ++r2)
                ps[(size_t)(row + r2) * OUT_F + col] = f2bf(acc[mt][nt][r2]);
        }
    }
}

// ---- Kernel C: out = fwht(sum_slices)*SV + bias  [f32 out] ----
__global__ __launch_bounds__(256) void k_post2(const unsigned short* __restrict__ pin,
                                               const float* __restrict__ SV,
                                               const float* __restrict__ bias,
                                               float* __restrict__ out) {
    __shared__ float lds[8224];
    const int r = blockIdx.x, t = threadIdx.x;
    float v[32];
#pragma unroll
    for (int j = 0; j < 32; ++j) v[j] = 0.f;
#pragma unroll 1
    for (int sl = 0; sl < NSL; ++sl) {
        const uint4* p = reinterpret_cast<const uint4*>(
            pin + (size_t)sl * NROWS * OUT_F + (size_t)r * OUT_F + t * 32);
#pragma unroll
        for (int q = 0; q < 4; ++q) {
            float a[8];
            unpack8(p[q], a);
#pragma unroll
            for (int j = 0; j < 8; ++j) v[q * 8 + j] += a[j];
        }
    }
    fwht8192(v, lds, t);
    const float4* svp = reinterpret_cast<const float4*>(SV);
    const float4* bip = reinterpret_cast<const float4*>(bias);
    float4* op = reinterpret_cast<float4*>(out + (size_t)r * OUT_F);
#pragma unroll
    for (int q = 0; q < 8; ++q) {
        float4 sv = svp[t * 8 + q], bi = bip[t * 8 + q], o;
        o.x = v[q * 4 + 0] * FWHT_SCALE * sv.x + bi.x;
        o.y = v[q * 4 + 1] * FWHT_SCALE * sv.y + bi.y;
        o.z = v[q * 4 + 2] * FWHT_SCALE * sv.z + bi.z;
        o.w = v[q * 4 + 3] * FWHT_SCALE * sv.w + bi.w;
        op[t * 8 + q] = o;
    }
}

extern "C" void kernel_launch(void* const* d_in, const int* in_sizes, int n_in,
                              void* d_out, int out_size, void* d_ws, size_t ws_size,
                              hipStream_t stream) {
    const float* in      = (const float*)d_in[0];
    const int*   Qidxs   = (const int*)d_in[1];
    const float* cb      = (const float*)d_in[2];
    const float* scaleWH = (const float*)d_in[3];
    const float* SU      = (const float*)d_in[4];
    const float* SV      = (const float*)d_in[5];
    const float* wscale  = (const float*)d_in[6];
    const float* bias    = (const float*)d_in[7];
    float* out = (float*)d_out;

    unsigned short* xt    = (unsigned short*)d_ws;                    // 2 MB (tiled)
    unsigned short* parts = (unsigned short*)((char*)d_ws
                            + (size_t)NROWS * IN_F * 2);              // 16 MB

    k_pre3<<<NROWS, 256, 0, stream>>>(in, scaleWH, SU, xt);
    k_gemm6<<<dim3(OUT_F / NTB, NSL), 256, 0, stream>>>(xt, Qidxs, cb, wscale, parts);
    k_post2<<<NROWS, 256, 0, stream>>>(parts, SV, bias, out);
}